// Round 9
// baseline (280.014 us; speedup 1.0000x reference)
//
#include <hip/hip_runtime.h>
#include <hip/hip_bf16.h>
#include <math.h>

// Problem constants
#define BB 2
#define SS 2048
#define DD 1024
#define HH 16
#define DH 64

typedef __bf16 bf16;
typedef __bf16 bf16x8 __attribute__((ext_vector_type(8)));
typedef __bf16 bf16x4 __attribute__((ext_vector_type(4)));
typedef short short4v __attribute__((ext_vector_type(4)));
typedef float f32x4 __attribute__((ext_vector_type(4)));

static const size_t NTOK  = (size_t)BB * SS * DD;   // 4,194,304
static const size_t STATN = (size_t)BB * HH * SS;   // 65,536

// Q pre-scaled by 0.125 in qkv epilogue; softmax = exp(s)/sum exp(s), no max-sub.

__device__ __forceinline__ f32x4 mfma16(bf16x8 a, bf16x8 b, f32x4 c) {
    return __builtin_amdgcn_mfma_f32_16x16x32_bf16(a, b, c, 0, 0, 0);
}
__device__ __forceinline__ f32x4 mfma16k16(short4v a, short4v b, f32x4 c) {
    return __builtin_amdgcn_mfma_f32_16x16x16bf16_1k(a, b, c, 0, 0, 0);
}
__device__ __forceinline__ void gload_lds16(const void* g, void* l) {
    __builtin_amdgcn_global_load_lds(
        (const __attribute__((address_space(1))) void*)g,
        (__attribute__((address_space(3))) void*)l, 16, 0, 0);
}
__device__ __forceinline__ bf16x8 cvt8(float4 a, float4 b) {
    bf16x8 r;
    r[0] = (bf16)a.x; r[1] = (bf16)a.y; r[2] = (bf16)a.z; r[3] = (bf16)a.w;
    r[4] = (bf16)b.x; r[5] = (bf16)b.y; r[6] = (bf16)b.z; r[7] = (bf16)b.w;
    return r;
}

// counted-vmcnt waits (T4): "memory" clobber pins surrounding mem ops
#define WAITV(N)  asm volatile("s_waitcnt vmcnt(" #N ")" ::: "memory")
#define BAR()     __builtin_amdgcn_s_barrier()
// LDS-only barrier: drains LDS ops for cross-wave visibility but leaves
// global loads in flight (unlike __syncthreads' vmcnt(0) drain)
#define LBAR() do { asm volatile("s_waitcnt lgkmcnt(0)" ::: "memory"); \
                    __builtin_amdgcn_s_barrier(); } while (0)

__global__ void signal_f(float* out, float v) {
    if (threadIdx.x == 0 && blockIdx.x == 0) out[0] = v;
}

// fp32 -> bf16 bulk convert, 8 elem/thread
__global__ __launch_bounds__(256) void cvt_bf16(
    const float* __restrict__ s, bf16* __restrict__ d)
{
    size_t i = ((size_t)blockIdx.x * 256 + threadIdx.x) * 8;
    float4 a = *(const float4*)(s + i);
    float4 b = *(const float4*)(s + i + 4);
    *(bf16x8*)(d + i) = cvt8(a, b);
}
// 3-matrix variant for Wq/Wk/Wv
__global__ __launch_bounds__(256) void cvt_w3(
    const float* __restrict__ w0, const float* __restrict__ w1,
    const float* __restrict__ w2, bf16* __restrict__ o0,
    bf16* __restrict__ o1, bf16* __restrict__ o2)
{
    const float* s = (blockIdx.y == 0) ? w0 : (blockIdx.y == 1) ? w1 : w2;
    bf16*        d = (blockIdx.y == 0) ? o0 : (blockIdx.y == 1) ? o1 : o2;
    size_t i = ((size_t)blockIdx.x * 256 + threadIdx.x) * 8;
    float4 a = *(const float4*)(s + i);
    float4 b = *(const float4*)(s + i + 4);
    *(bf16x8*)(d + i) = cvt8(a, b);
}

// ---------------------------------------------------------------------------
// qkv7: all three projections, one kernel (768 blocks = 3/CU).
// Two register stage-sets (loads issued 2 steps ahead of their ds_write).
// Barriers are LDS-only (LBAR): global loads stay in flight across them; the
// compiler emits COUNTED vmcnt from register deps (wait stage t0+1, keep
// t0+2 outstanding). All staging is register-based: no hand vmcnt needed.
// ---------------------------------------------------------------------------
#define LDP3 40

__global__ __launch_bounds__(256, 3) void qkv7(
    const float* __restrict__ Aq, const float* __restrict__ Ak,
    const float* __restrict__ Av,
    const bf16* __restrict__ Wqb, const bf16* __restrict__ Wkb,
    const bf16* __restrict__ Wvb,
    const float* __restrict__ bq, const float* __restrict__ bk,
    const float* __restrict__ bv,
    bf16* __restrict__ Qs, bf16* __restrict__ Ks, bf16* __restrict__ Vt)
{
    const int K = DD, N = DD;
    __shared__ bf16 As[2][128][LDP3];
    __shared__ bf16 Bs[2][128][LDP3];

    int t = (int)threadIdx.x;
    int lane = t & 63, w = t >> 6;
    int wm = w >> 1, wn = w & 1;
    int c16 = lane & 15, quad = lane >> 4, ko = quad << 3;

    int x = blockIdx.x & 7;            // XCD
    int j = blockIdx.x >> 3;           // 0..95
    int proj = j >> 5;
    int rem  = j & 31;
    int tm = x + ((rem >> 3) << 3);    // 0..31
    int tn = rem & 7;                  // 0..7

    const float* A    = (proj == 0) ? Aq : (proj == 1) ? Ak : Av;
    const bf16*  W    = (proj == 0) ? Wqb : (proj == 1) ? Wkb : Wvb;
    const float* bias = (proj == 0) ? bq : (proj == 1) ? bk : bv;
    bf16*        C    = (proj == 0) ? Qs : (proj == 1) ? Ks : Vt;
    float osc = (proj == 0) ? 0.125f : 1.0f;

    int arow = t >> 1, acb = (t & 1) * 16;   // 128 rows x 32, 16 elem/thread
    const float* abase = A + (size_t)(tm * 128 + arow) * K + acb;
    const bf16*  wbase = W + (size_t)(tn * 128 + arow) * K + acb;

    f32x4 acc[4][4];
#pragma unroll
    for (int i = 0; i < 4; ++i)
#pragma unroll
        for (int q = 0; q < 4; ++q) acc[i][q] = (f32x4){0.f, 0.f, 0.f, 0.f};

    float4 aA0, aA1, aA2, aA3, aB0, aB1, aB2, aB3;
    bf16x8 wA0, wA1, wB0, wB1;

    // prologue: stage0 -> regs -> LDS[0]; stage1 -> regs (stays in flight)
    aA0 = *(const float4*)(abase);     aA1 = *(const float4*)(abase + 4);
    aA2 = *(const float4*)(abase + 8); aA3 = *(const float4*)(abase + 12);
    wA0 = *(const bf16x8*)(wbase);     wA1 = *(const bf16x8*)(wbase + 8);
    *(bf16x8*)&As[0][arow][acb]     = cvt8(aA0, aA1);
    *(bf16x8*)&As[0][arow][acb + 8] = cvt8(aA2, aA3);
    *(bf16x8*)&Bs[0][arow][acb]     = wA0;
    *(bf16x8*)&Bs[0][arow][acb + 8] = wA1;
    aB0 = *(const float4*)(abase + 32);     aB1 = *(const float4*)(abase + 36);
    aB2 = *(const float4*)(abase + 40);     aB3 = *(const float4*)(abase + 44);
    wB0 = *(const bf16x8*)(wbase + 32);     wB1 = *(const bf16x8*)(wbase + 40);
    LBAR();

    // step T0: issue loads for stage T0+2; compute LDS[BI]; write stage T0+1
    // (regs, loaded 2 steps ago) into LDS[BI^1]; LDS-only barrier.
    auto qstep = [&](int T0, int BI,
                     float4& cA0, float4& cA1, float4& cA2, float4& cA3,
                     bf16x8& cW0, bf16x8& cW1,
                     float4& nA0, float4& nA1, float4& nA2, float4& nA3,
                     bf16x8& nW0, bf16x8& nW1) {
        if (T0 + 2 < 32) {
            const float* ap = abase + (T0 + 2) * 32;
            nA0 = *(const float4*)(ap);     nA1 = *(const float4*)(ap + 4);
            nA2 = *(const float4*)(ap + 8); nA3 = *(const float4*)(ap + 12);
            const bf16* wp = wbase + (T0 + 2) * 32;
            nW0 = *(const bf16x8*)(wp);     nW1 = *(const bf16x8*)(wp + 8);
        }
        bf16x8 af[4], bfr[4];
#pragma unroll
        for (int mt = 0; mt < 4; ++mt)
            af[mt] = *(const bf16x8*)&As[BI][wm * 64 + mt * 16 + c16][ko];
#pragma unroll
        for (int nt = 0; nt < 4; ++nt)
            bfr[nt] = *(const bf16x8*)&Bs[BI][wn * 64 + nt * 16 + c16][ko];
#pragma unroll
        for (int mt = 0; mt < 4; ++mt)
#pragma unroll
            for (int nt = 0; nt < 4; ++nt)
                acc[mt][nt] = mfma16(af[mt], bfr[nt], acc[mt][nt]);
        if (T0 + 1 < 32) {
            *(bf16x8*)&As[BI ^ 1][arow][acb]     = cvt8(cA0, cA1);
            *(bf16x8*)&As[BI ^ 1][arow][acb + 8] = cvt8(cA2, cA3);
            *(bf16x8*)&Bs[BI ^ 1][arow][acb]     = cW0;
            *(bf16x8*)&Bs[BI ^ 1][arow][acb + 8] = cW1;
        }
        LBAR();
    };

    for (int i = 0; i < 16; ++i) {
        qstep(2 * i,     0, aB0, aB1, aB2, aB3, wB0, wB1,
                            aA0, aA1, aA2, aA3, wA0, wA1);
        qstep(2 * i + 1, 1, aA0, aA1, aA2, aA3, wA0, wA1,
                            aB0, aB1, aB2, aB3, wB0, wB1);
    }

    // epilogue: D col = lane&15 (n), row = quad*4+r (m)
#pragma unroll
    for (int nt = 0; nt < 4; ++nt) {
        int col = tn * 128 + wn * 64 + nt * 16 + c16;
        float bv2 = bias[col];
#pragma unroll
        for (int mt = 0; mt < 4; ++mt) {
            int r0 = tm * 128 + wm * 64 + mt * 16 + quad * 4;
            if (proj == 2) {           // transposed V output
                int b2 = r0 >> 11;
                int s  = r0 & (SS - 1);
                size_t base = ((size_t)b2 * N + col) * SS + s;
                bf16x4 pk;
#pragma unroll
                for (int r = 0; r < 4; ++r)
                    pk[r] = (bf16)(acc[mt][nt][r] + bv2);
                *(bf16x4*)&C[base] = pk;
            } else {
#pragma unroll
                for (int r = 0; r < 4; ++r)
                    C[(size_t)(r0 + r) * N + col] =
                        (bf16)((acc[mt][nt][r] + bv2) * osc);
            }
        }
    }
}

// ---------------------------------------------------------------------------
// gemm7: out-projection, 512 blocks x 4 waves (2 blocks/CU).
// C[4096,1024]f32 = ctx(bf16) @ WoB(bf16)^T + bo. 128(M)x64(N) tile, BK=32.
// Both operands via global_load_lds (3 gloads/wave/stage), 4 buffers,
// XOR-swizzled, 2 stages ahead, counted vmcnt(6)/(3)/(0).
// ---------------------------------------------------------------------------
__global__ __launch_bounds__(256) void gemm7(
    const bf16* __restrict__ A, const bf16* __restrict__ W,
    const float* __restrict__ bias, float* __restrict__ C)
{
    __shared__ __align__(16) bf16 As[4][128][32];   // 32 KB
    __shared__ __align__(16) bf16 Bs[4][64][32];    // 16 KB

    int t = (int)threadIdx.x;
    int lane = t & 63, w = t >> 6;                  // 4 waves
    int wm = w >> 1, wn = w & 1;
    int c16 = lane & 15, quad = lane >> 4, ko = quad << 3;

    int x = blockIdx.x & 7, j = blockIdx.x >> 3;    // 512 blocks, j 0..63
    int tm = x + ((j >> 4) << 3);                   // 0..31
    int tn = j & 15;                                // 0..15

    // staging: wave w -> A row-groups 2w,2w+1 (16 rows each) + W rows w*16..
    int srow = lane >> 2;                 // 0..15 within group
    int schk = (lane & 3) ^ (srow & 3);   // inverse swizzle (64B rows)
    const bf16* asrc0 = A + (size_t)(tm * 128 + (2 * w) * 16 + srow) * DD + schk * 8;
    const bf16* asrc1 = asrc0 + (size_t)16 * DD;
    const bf16* wsrc  = W + (size_t)(tn * 64 + w * 16 + srow) * DD + schk * 8;
    char* adst0 = (char*)&As[0][0][0] + (2 * w) * 1024;
    char* adst1 = adst0 + 1024;
    char* wdst  = (char*)&Bs[0][0][0] + w * 1024;

    f32x4 acc[4][2];
#pragma unroll
    for (int i = 0; i < 4; ++i)
#pragma unroll
        for (int q = 0; q < 2; ++q) acc[i][q] = (f32x4){0.f, 0.f, 0.f, 0.f};

#pragma unroll
    for (int s = 0; s < 2; ++s) {
        gload_lds16(asrc0 + s * 32, adst0 + s * 8192);
        gload_lds16(asrc1 + s * 32, adst1 + s * 8192);
        gload_lds16(wsrc  + s * 32, wdst  + s * 4096);
    }

    for (int t0 = 0; t0 < 32; ++t0) {
        if (t0 + 2 < 32) {
            int s = t0 + 2;
            gload_lds16(asrc0 + s * 32, adst0 + (s & 3) * 8192);
            gload_lds16(asrc1 + s * 32, adst1 + (s & 3) * 8192);
            gload_lds16(wsrc  + s * 32, wdst  + (s & 3) * 4096);
        }
        if (t0 < 30)      { WAITV(6); }   // retire stage t0, keep 2 in flight
        else if (t0 == 30){ WAITV(3); }
        else              { WAITV(0); }
        BAR();
        const char* al = (const char*)&As[0][0][0] + (t0 & 3) * 8192;
        const char* wl = (const char*)&Bs[0][0][0] + (t0 & 3) * 4096;
        bf16x8 af[4], bfr[2];
#pragma unroll
        for (int mt = 0; mt < 4; ++mt) {
            int row = wm * 64 + mt * 16 + c16;
            af[mt] = *(const bf16x8*)(al + row * 64 + ((quad ^ (row & 3)) << 4));
        }
#pragma unroll
        for (int nt = 0; nt < 2; ++nt) {
            int row = wn * 32 + nt * 16 + c16;
            bfr[nt] = *(const bf16x8*)(wl + row * 64 + ((quad ^ (row & 3)) << 4));
        }
#pragma unroll
        for (int mt = 0; mt < 4; ++mt)
#pragma unroll
            for (int nt = 0; nt < 2; ++nt)
                acc[mt][nt] = mfma16(af[mt], bfr[nt], acc[mt][nt]);
    }

#pragma unroll
    for (int nt = 0; nt < 2; ++nt) {
        int col = tn * 64 + wn * 32 + nt * 16 + c16;
        float bv = bias[col];
#pragma unroll
        for (int mt = 0; mt < 4; ++mt) {
            int r0 = tm * 128 + wm * 64 + mt * 16 + quad * 4;
#pragma unroll
            for (int r = 0; r < 4; ++r)
                C[(size_t)(r0 + r) * DD + col] = acc[mt][nt][r] + bv;
        }
    }
}

// ---------------------------------------------------------------------------
// col_stats5: partial column sums z_k = sum_{q in half} exp(s[q,k]).
// 512 blocks (2/CU); attn combines rz = 1/(z0+z1) in its prologue.
// ---------------------------------------------------------------------------
__global__ __launch_bounds__(512) void col_stats5(
    const bf16* __restrict__ Q, const bf16* __restrict__ Km,
    float* __restrict__ z0S, float* __restrict__ z1S)
{
    __shared__ __align__(16) bf16 Qlds[4][32][64];   // 16 KB

    int t = (int)threadIdx.x;
    int w = t >> 6, lane = t & 63;
    int c16 = lane & 15, quad = lane >> 4, ko = quad << 3;

    int x = blockIdx.x & 7, j = blockIdx.x >> 3;     // j 0..63
    int bh = ((j >> 4) << 3) + x;                    // 4 bh-groups
    int qh = (j >> 3) & 1;
    int kg = j & 7;
    int b = bh >> 4, h = bh & (HH - 1);
    int kbase = kg * 256 + w * 32;
    int q0base = qh * 1024;
    float* zS = qh ? z1S : z0S;

    bf16x8 kf[2][2];
#pragma unroll
    for (int g = 0; g < 2; ++g) {
        const bf16* kp =
            Km + ((size_t)(b * SS + kbase + g * 16 + c16)) * DD + h * DH + ko;
        kf[g][0] = *(const bf16x8*)kp;
        kf[g][1] = *(const bf16x8*)(kp + 32);
    }

    int srow  = ((w & 3) << 3) + (lane >> 3);
    int schnk = (lane & 7) ^ (srow & 7);
    const bf16* gsrc =
        Q + ((size_t)(b * SS + q0base + srow)) * DD + h * DH + schnk * 8;
    int ldsOff = (w & 3) << 10;
    bool stager = (w < 4);

    float z[2][4] = {{0.f,0.f,0.f,0.f},{0.f,0.f,0.f,0.f}};

    if (stager) {
        gload_lds16(gsrc, (char*)&Qlds[0][0][0] + ldsOff);
        gload_lds16(gsrc + (size_t)32 * DD, (char*)&Qlds[1][0][0] + ldsOff);
    }

    for (int t0 = 0; t0 < 32; ++t0) {
        if (t0 + 2 < 32 && stager)
            gload_lds16(gsrc + (size_t)(t0 + 2) * 32 * DD,
                        (char*)&Qlds[(t0 + 2) & 3][0][0] + ldsOff);
        if (t0 < 30)      { WAITV(2); }
        else if (t0 == 30){ WAITV(1); }
        else              { WAITV(0); }
        BAR();
        const char* ql = (const char*)&Qlds[t0 & 3][0][0];
#pragma unroll
        for (int qs = 0; qs < 2; ++qs) {
            int row = qs * 16 + c16;
            int p0  = quad ^ (row & 7);
            bf16x8 qf0 = *(const bf16x8*)(ql + row * 128 + p0 * 16);
            bf16x8 qf1 = *(const bf16x8*)(ql + row * 128 + (p0 ^ 4) * 16);
#pragma unroll
            for (int g = 0; g < 2; ++g) {
                f32x4 a = {0.f, 0.f, 0.f, 0.f};
                a = mfma16(kf[g][0], qf0, a);
                a = mfma16(kf[g][1], qf1, a);
#pragma unroll
                for (int r = 0; r < 4; ++r)
                    z[g][r] += __expf(a[r]);
            }
        }
    }

#pragma unroll
    for (int g = 0; g < 2; ++g)
#pragma unroll
        for (int r = 0; r < 4; ++r) {
#pragma unroll
            for (int off = 1; off < 16; off <<= 1)
                z[g][r] += __shfl_xor(z[g][r], off, 64);
        }
    if (c16 == 0) {
        size_t base = (size_t)bh * SS + kbase + quad * 4;
#pragma unroll
        for (int g = 0; g < 2; ++g)
#pragma unroll
            for (int r = 0; r < 4; ++r)
                zS[base + g * 16 + r] = z[g][r];
    }
}

// ---------------------------------------------------------------------------
// attn_ctx8: ctx = softmax-over-q weighted V.
// 512 blocks x 4 waves = 2 blocks/CU (TLP doubles vs v7's 1 block/CU).
// Each wave stages 1 K-gload + 1 V-gload per stage; 4 buffers, 2 ahead,
// counted vmcnt(4)/(2)/(0). rz combined to LDS in a fully-retired prologue.
// ---------------------------------------------------------------------------
__global__ __launch_bounds__(256) void attn_ctx8(
    const bf16* __restrict__ Q, const bf16* __restrict__ Km,
    const bf16* __restrict__ Vt, const float* __restrict__ z0S,
    const float* __restrict__ z1S, bf16* __restrict__ ctx)
{
    __shared__ __align__(16) char lds[4][8192];   // per buf: K 4KB | V 4KB
    __shared__ __align__(16) float rzlds[2048];   // 8 KB

    int t = (int)threadIdx.x;
    int w = t >> 6, lane = t & 63;                // 4 waves
    int c16 = lane & 15, quad = lane >> 4, ko = quad << 3;

    int bid = blockIdx.x;                         // 512 = 8 xcd * 4 bh * 16 qg
    int x = bid & 7, j = bid >> 3;                // j 0..63
    int bh = ((j >> 4) << 3) + x;
    int qg = j & 15;
    int b = bh >> 4, h = bh & (HH - 1);
    int qt0 = qg * 8 + w * 2;                     // wave: q-tiles qt0, qt0+1

    const bf16* qp0 = Q + ((size_t)(b * SS + qt0 * 16 + c16)) * DD + h * DH + ko;
    bf16x8 qa0 = *(const bf16x8*)qp0;
    bf16x8 qa1 = *(const bf16x8*)(qp0 + 32);
    const bf16* qp1 = qp0 + (size_t)16 * DD;
    bf16x8 qb0 = *(const bf16x8*)qp1;
    bf16x8 qb1 = *(const bf16x8*)(qp1 + 32);

    // prologue A: rz = 1/(z0+z1) into LDS (plain loads, fully retired)
#pragma unroll
    for (int hh = 0; hh < 2; ++hh) {
        int idx = hh * 256 + t;                   // 0..511
        f32x4 z0 = *(const f32x4*)(z0S + (size_t)bh * SS + idx * 4);
        f32x4 z1 = *(const f32x4*)(z1S + (size_t)bh * SS + idx * 4);
        f32x4 rz;
#pragma unroll
        for (int r = 0; r < 4; ++r) rz[r] = 1.0f / (z0[r] + z1[r]);
        *(f32x4*)&rzlds[idx * 4] = rz;
    }
    __syncthreads();

    // staging: wave w covers K rows w*8..+7 and V rows w*16..+15 (1 gload ea)
    int krow = (w << 3) + (lane >> 3);
    int kchk = (lane & 7) ^ (krow & 7);
    const bf16* kgsrc = Km + ((size_t)(b * SS + krow)) * DD + h * DH + kchk * 8;
    int kldsOff = w << 10;

    int vrow = (w << 4) + (lane >> 2);
    int vchk = (lane & 3) ^ ((lane >> 3) & 3);    // (row>>1)&3 swizzle
    const bf16* vgsrc = Vt + ((size_t)(b * DD + h * DH + vrow)) * SS + vchk * 8;
    int vldsOff = 4096 + (w << 10);

    int kread  = c16 * 128 + ((quad ^ (c16 & 7)) << 4);
    int vread0 = c16 * 64 + (((quad >> 1) ^ ((c16 >> 1) & 3)) << 4)
               + ((quad & 1) << 3);

    f32x4 oa[4] = {{0,0,0,0},{0,0,0,0},{0,0,0,0},{0,0,0,0}};
    f32x4 ob[4] = {{0,0,0,0},{0,0,0,0},{0,0,0,0},{0,0,0,0}};

    // prologue B: stages 0,1 (2 gloads per wave per stage)
#pragma unroll
    for (int s = 0; s < 2; ++s) {
        gload_lds16(kgsrc + (size_t)(s * 32) * DD, &lds[s][kldsOff]);
        gload_lds16(vgsrc + s * 32, &lds[s][vldsOff]);
    }

    for (int t0 = 0; t0 < 64; ++t0) {
        if (t0 + 2 < 64) {
            int s = t0 + 2;
            gload_lds16(kgsrc + (size_t)(s * 32) * DD, &lds[s & 3][kldsOff]);
            gload_lds16(vgsrc + s * 32, &lds[s & 3][vldsOff]);
        }
        if (t0 < 62)      { WAITV(4); }
        else if (t0 == 62){ WAITV(2); }
        else              { WAITV(0); }
        BAR();
        const char* kl = &lds[t0 & 3][0];
        const char* vl = &lds[t0 & 3][4096];
#pragma unroll
        for (int ks = 0; ks < 2; ++ks) {
            int kb0 = kread + ks * 2048;
            bf16x8 kf0 = *(const bf16x8*)(kl + kb0);
            bf16x8 kf1 = *(const bf16x8*)(kl + (kb0 ^ 64));
            f32x4 z4 = *(const f32x4*)&rzlds[t0 * 32 + ks * 16 + quad * 4];
            f32x4 sa = {0,0,0,0}, sb = {0,0,0,0};
            sa = mfma16(kf0, qa0, sa);
            sa = mfma16(kf1, qa1, sa);
            sb = mfma16(kf0, qb0, sb);
            sb = mfma16(kf1, qb1, sb);

            union { bf16x4 b; short4v s; } pa, pb;
#pragma unroll
            for (int r = 0; r < 4; ++r) {
                pa.b[r] = (bf16)(__expf(sa[r]) * z4[r]);
                pb.b[r] = (bf16)(__expf(sb[r]) * z4[r]);
            }
            int vb0 = ks ? (vread0 ^ 32) : vread0;
#pragma unroll
            for (int dt = 0; dt < 4; ++dt) {
                short4v vf = *(const short4v*)(vl + vb0 + dt * 1024);
                oa[dt] = mfma16k16(pa.s, vf, oa[dt]);
                ob[dt] = mfma16k16(pb.s, vf, ob[dt]);
            }
        }
    }

    size_t orow = ((size_t)(b * SS + qt0 * 16 + quad * 4)) * DD + h * DH + c16;
#pragma unroll
    for (int dt = 0; dt < 4; ++dt)
#pragma unroll
        for (int r = 0; r < 4; ++r) {
            ctx[orow + (size_t)r * DD + dt * 16] = (bf16)oa[dt][r];
            ctx[orow + (size_t)(16 + r) * DD + dt * 16] = (bf16)ob[dt][r];
        }
}

extern "C" void kernel_launch(void* const* d_in, const int* in_sizes, int n_in,
                              void* d_out, int out_size, void* d_ws, size_t ws_size,
                              hipStream_t stream) {
    const float* query = (const float*)d_in[0];
    const float* key   = (const float*)d_in[1];
    const float* value = (const float*)d_in[2];
    const float* Wq = (const float*)d_in[3];
    const float* bq = (const float*)d_in[4];
    const float* Wk = (const float*)d_in[5];
    const float* bk = (const float*)d_in[6];
    const float* Wv = (const float*)d_in[7];
    const float* bv = (const float*)d_in[8];
    const float* Wo = (const float*)d_in[9];
    const float* bo = (const float*)d_in[10];
    float* out = (float*)d_out;

    if (n_in != 11 || in_sizes[0] != (int)NTOK || in_sizes[3] != DD * DD ||
        in_sizes[4] != DD || out_size != (int)NTOK) {
        hipLaunchKernelGGL(signal_f, dim3(1), dim3(64), 0, stream, out, -64.0f);
        return;
    }

    bf16* Qs  = (bf16*)d_ws;          // 0.125-scaled Q projection
    bf16* Ks  = Qs + NTOK;
    bf16* Vt  = Ks + NTOK;            // transposed V: [b][d][s]
    bf16* Cs  = Vt + NTOK;            // ctx; pre-attn aliased as bf16 weights
    float* z0S = (float*)(Cs + NTOK); // partial column sums (q-half 0 / 1)
    float* z1S = z0S + STATN;

    bf16* Wqb = Cs;                   // 3x 2MB bf16 weights (dead until attn)
    bf16* Wkb = Cs + (size_t)DD * DD;
    bf16* Wvb = Cs + (size_t)2 * DD * DD;
    bf16* WoB = Qs;                   // Wo bf16, written AFTER attn (Qs dead)

    hipLaunchKernelGGL(cvt_w3, dim3(512, 3), dim3(256), 0, stream,
                       Wq, Wk, Wv, Wqb, Wkb, Wvb);

    hipLaunchKernelGGL(qkv7, dim3(768), dim3(256), 0, stream,
                       query, key, value, Wqb, Wkb, Wvb, bq, bk, bv,
                       Qs, Ks, Vt);

    hipLaunchKernelGGL(col_stats5, dim3(512), dim3(512), 0, stream,
                       Qs, Ks, z0S, z1S);

    hipLaunchKernelGGL(attn_ctx8, dim3(512), dim3(256), 0, stream,
                       Qs, Ks, Vt, z0S, z1S, Cs);

    hipLaunchKernelGGL(cvt_bf16, dim3(512), dim3(256), 0, stream, Wo, WoB);

    hipLaunchKernelGGL(gemm7, dim3(512), dim3(256), 0, stream, Cs, WoB, bo, out);
}

// Round 10
// 277.485 us; speedup vs baseline: 1.0091x; 1.0091x over previous
//
#include <hip/hip_runtime.h>
#include <hip/hip_bf16.h>
#include <math.h>

// Problem constants
#define BB 2
#define SS 2048
#define DD 1024
#define HH 16
#define DH 64

typedef __bf16 bf16;
typedef __bf16 bf16x8 __attribute__((ext_vector_type(8)));
typedef __bf16 bf16x4 __attribute__((ext_vector_type(4)));
typedef short short4v __attribute__((ext_vector_type(4)));
typedef float f32x4 __attribute__((ext_vector_type(4)));

static const size_t NTOK  = (size_t)BB * SS * DD;   // 4,194,304
static const size_t STATN = (size_t)BB * HH * SS;   // 65,536

// Q pre-scaled by 0.125 in qkv epilogue; softmax = exp(s)/sum exp(s), no max-sub.

__device__ __forceinline__ f32x4 mfma16(bf16x8 a, bf16x8 b, f32x4 c) {
    return __builtin_amdgcn_mfma_f32_16x16x32_bf16(a, b, c, 0, 0, 0);
}
__device__ __forceinline__ f32x4 mfma16k16(short4v a, short4v b, f32x4 c) {
    return __builtin_amdgcn_mfma_f32_16x16x16bf16_1k(a, b, c, 0, 0, 0);
}
__device__ __forceinline__ void gload_lds16(const void* g, void* l) {
    __builtin_amdgcn_global_load_lds(
        (const __attribute__((address_space(1))) void*)g,
        (__attribute__((address_space(3))) void*)l, 16, 0, 0);
}
__device__ __forceinline__ bf16x8 cvt8(float4 a, float4 b) {
    bf16x8 r;
    r[0] = (bf16)a.x; r[1] = (bf16)a.y; r[2] = (bf16)a.z; r[3] = (bf16)a.w;
    r[4] = (bf16)b.x; r[5] = (bf16)b.y; r[6] = (bf16)b.z; r[7] = (bf16)b.w;
    return r;
}

// counted-vmcnt waits (T4): "memory" clobber pins surrounding mem ops
#define WAITV(N)  asm volatile("s_waitcnt vmcnt(" #N ")" ::: "memory")
#define BAR()     __builtin_amdgcn_s_barrier()
// LDS-only barrier: drains LDS ops for cross-wave visibility but leaves
// global loads in flight (unlike __syncthreads' vmcnt(0) drain)
#define LBAR() do { asm volatile("s_waitcnt lgkmcnt(0)" ::: "memory"); \
                    __builtin_amdgcn_s_barrier(); } while (0)

__global__ void signal_f(float* out, float v) {
    if (threadIdx.x == 0 && blockIdx.x == 0) out[0] = v;
}

// fp32 -> bf16 bulk convert, 8 elem/thread
__global__ __launch_bounds__(256) void cvt_bf16(
    const float* __restrict__ s, bf16* __restrict__ d)
{
    size_t i = ((size_t)blockIdx.x * 256 + threadIdx.x) * 8;
    float4 a = *(const float4*)(s + i);
    float4 b = *(const float4*)(s + i + 4);
    *(bf16x8*)(d + i) = cvt8(a, b);
}
// 3-matrix variant for Wq/Wk/Wv
__global__ __launch_bounds__(256) void cvt_w3(
    const float* __restrict__ w0, const float* __restrict__ w1,
    const float* __restrict__ w2, bf16* __restrict__ o0,
    bf16* __restrict__ o1, bf16* __restrict__ o2)
{
    const float* s = (blockIdx.y == 0) ? w0 : (blockIdx.y == 1) ? w1 : w2;
    bf16*        d = (blockIdx.y == 0) ? o0 : (blockIdx.y == 1) ? o1 : o2;
    size_t i = ((size_t)blockIdx.x * 256 + threadIdx.x) * 8;
    float4 a = *(const float4*)(s + i);
    float4 b = *(const float4*)(s + i + 4);
    *(bf16x8*)(d + i) = cvt8(a, b);
}

// ---------------------------------------------------------------------------
// qkv8: all three projections, one kernel (768 blocks = 3/CU).
// = qkv7 (2-deep register staging, LDS-only barriers, compiler-counted
// vmcnt) but with the bank-conflict-free [128][32] XOR-swizzled LDS layout
// (write chunk c^(row&3), read chunk quad^(row&3)) replacing the LDP=40 pad
// whose 80B rows put all 64 lanes on 8/32 bank-groups (6.3M conflict cycles).
// ---------------------------------------------------------------------------
__global__ __launch_bounds__(256, 3) void qkv8(
    const float* __restrict__ Aq, const float* __restrict__ Ak,
    const float* __restrict__ Av,
    const bf16* __restrict__ Wqb, const bf16* __restrict__ Wkb,
    const bf16* __restrict__ Wvb,
    const float* __restrict__ bq, const float* __restrict__ bk,
    const float* __restrict__ bv,
    bf16* __restrict__ Qs, bf16* __restrict__ Ks, bf16* __restrict__ Vt)
{
    const int K = DD, N = DD;
    __shared__ __align__(16) bf16 As[2][128][32];   // 16 KB, swizzled
    __shared__ __align__(16) bf16 Bs[2][128][32];   // 16 KB, swizzled

    int t = (int)threadIdx.x;
    int lane = t & 63, w = t >> 6;
    int wm = w >> 1, wn = w & 1;
    int c16 = lane & 15, quad = lane >> 4, ko = quad << 3;

    int x = blockIdx.x & 7;            // XCD
    int j = blockIdx.x >> 3;           // 0..95
    int proj = j >> 5;
    int rem  = j & 31;
    int tm = x + ((rem >> 3) << 3);    // 0..31
    int tn = rem & 7;                  // 0..7

    const float* A    = (proj == 0) ? Aq : (proj == 1) ? Ak : Av;
    const bf16*  W    = (proj == 0) ? Wqb : (proj == 1) ? Wkb : Wvb;
    const float* bias = (proj == 0) ? bq : (proj == 1) ? bk : bv;
    bf16*        C    = (proj == 0) ? Qs : (proj == 1) ? Ks : Vt;
    float osc = (proj == 0) ? 0.125f : 1.0f;

    int arow = t >> 1;                       // staged row 0..127
    int acb  = (t & 1) * 16;                 // elem offset 0 / 16
    // swizzled write chunks for this thread's two 16B stores
    int wc0 = ((t & 1) * 2)     ^ (arow & 3);
    int wc1 = ((t & 1) * 2 + 1) ^ (arow & 3);
    const float* abase = A + (size_t)(tm * 128 + arow) * K + acb;
    const bf16*  wbase = W + (size_t)(tn * 128 + arow) * K + acb;

    // swizzled read base offsets (bytes within a [128][32] buffer)
    int rsw   = (quad ^ (c16 & 3)) << 4;     // chunk quad ^ (row&3), row%4=c16%4
    int aroff = (wm * 64 + c16) * 64 + rsw;  // + mt*1024
    int broff = (wn * 64 + c16) * 64 + rsw;  // + nt*1024

    f32x4 acc[4][4];
#pragma unroll
    for (int i = 0; i < 4; ++i)
#pragma unroll
        for (int q = 0; q < 4; ++q) acc[i][q] = (f32x4){0.f, 0.f, 0.f, 0.f};

    float4 aA0, aA1, aA2, aA3, aB0, aB1, aB2, aB3;
    bf16x8 wA0, wA1, wB0, wB1;

    // prologue: stage0 -> regs -> LDS[0]; stage1 -> regs (stays in flight)
    aA0 = *(const float4*)(abase);     aA1 = *(const float4*)(abase + 4);
    aA2 = *(const float4*)(abase + 8); aA3 = *(const float4*)(abase + 12);
    wA0 = *(const bf16x8*)(wbase);     wA1 = *(const bf16x8*)(wbase + 8);
    {
        char* ab = (char*)&As[0][arow][0];
        char* bb = (char*)&Bs[0][arow][0];
        *(bf16x8*)(ab + wc0 * 16) = cvt8(aA0, aA1);
        *(bf16x8*)(ab + wc1 * 16) = cvt8(aA2, aA3);
        *(bf16x8*)(bb + wc0 * 16) = wA0;
        *(bf16x8*)(bb + wc1 * 16) = wA1;
    }
    aB0 = *(const float4*)(abase + 32);     aB1 = *(const float4*)(abase + 36);
    aB2 = *(const float4*)(abase + 40);     aB3 = *(const float4*)(abase + 44);
    wB0 = *(const bf16x8*)(wbase + 32);     wB1 = *(const bf16x8*)(wbase + 40);
    LBAR();

    auto qstep = [&](int T0, int BI,
                     float4& cA0, float4& cA1, float4& cA2, float4& cA3,
                     bf16x8& cW0, bf16x8& cW1,
                     float4& nA0, float4& nA1, float4& nA2, float4& nA3,
                     bf16x8& nW0, bf16x8& nW1) {
        if (T0 + 2 < 32) {
            const float* ap = abase + (T0 + 2) * 32;
            nA0 = *(const float4*)(ap);     nA1 = *(const float4*)(ap + 4);
            nA2 = *(const float4*)(ap + 8); nA3 = *(const float4*)(ap + 12);
            const bf16* wp = wbase + (T0 + 2) * 32;
            nW0 = *(const bf16x8*)(wp);     nW1 = *(const bf16x8*)(wp + 8);
        }
        const char* al = (const char*)&As[BI][0][0];
        const char* bl = (const char*)&Bs[BI][0][0];
        bf16x8 af[4], bfr[4];
#pragma unroll
        for (int mt = 0; mt < 4; ++mt)
            af[mt] = *(const bf16x8*)(al + aroff + mt * 1024);
#pragma unroll
        for (int nt = 0; nt < 4; ++nt)
            bfr[nt] = *(const bf16x8*)(bl + broff + nt * 1024);
#pragma unroll
        for (int mt = 0; mt < 4; ++mt)
#pragma unroll
            for (int nt = 0; nt < 4; ++nt)
                acc[mt][nt] = mfma16(af[mt], bfr[nt], acc[mt][nt]);
        if (T0 + 1 < 32) {
            char* ab = (char*)&As[BI ^ 1][arow][0];
            char* bb = (char*)&Bs[BI ^ 1][arow][0];
            *(bf16x8*)(ab + wc0 * 16) = cvt8(cA0, cA1);
            *(bf16x8*)(ab + wc1 * 16) = cvt8(cA2, cA3);
            *(bf16x8*)(bb + wc0 * 16) = cW0;
            *(bf16x8*)(bb + wc1 * 16) = cW1;
        }
        LBAR();
    };

    for (int i = 0; i < 16; ++i) {
        qstep(2 * i,     0, aB0, aB1, aB2, aB3, wB0, wB1,
                            aA0, aA1, aA2, aA3, wA0, wA1);
        qstep(2 * i + 1, 1, aA0, aA1, aA2, aA3, wA0, wA1,
                            aB0, aB1, aB2, aB3, wB0, wB1);
    }

    // epilogue: D col = lane&15 (n), row = quad*4+r (m)
#pragma unroll
    for (int nt = 0; nt < 4; ++nt) {
        int col = tn * 128 + wn * 64 + nt * 16 + c16;
        float bv2 = bias[col];
#pragma unroll
        for (int mt = 0; mt < 4; ++mt) {
            int r0 = tm * 128 + wm * 64 + mt * 16 + quad * 4;
            if (proj == 2) {           // transposed V output
                int b2 = r0 >> 11;
                int s  = r0 & (SS - 1);
                size_t base = ((size_t)b2 * N + col) * SS + s;
                bf16x4 pk;
#pragma unroll
                for (int r = 0; r < 4; ++r)
                    pk[r] = (bf16)(acc[mt][nt][r] + bv2);
                *(bf16x4*)&C[base] = pk;
            } else {
#pragma unroll
                for (int r = 0; r < 4; ++r)
                    C[(size_t)(r0 + r) * N + col] =
                        (bf16)((acc[mt][nt][r] + bv2) * osc);
            }
        }
    }
}

// ---------------------------------------------------------------------------
// gemm7: out-projection, 512 blocks x 4 waves (2-3 blocks/CU).
// Both operands via global_load_lds, XOR-swizzled, 4 buffers, 2 ahead,
// counted vmcnt(6)/(3)/(0).
// ---------------------------------------------------------------------------
__global__ __launch_bounds__(256) void gemm7(
    const bf16* __restrict__ A, const bf16* __restrict__ W,
    const float* __restrict__ bias, float* __restrict__ C)
{
    __shared__ __align__(16) bf16 As[4][128][32];   // 32 KB
    __shared__ __align__(16) bf16 Bs[4][64][32];    // 16 KB

    int t = (int)threadIdx.x;
    int lane = t & 63, w = t >> 6;                  // 4 waves
    int wm = w >> 1, wn = w & 1;
    int c16 = lane & 15, quad = lane >> 4, ko = quad << 3;

    int x = blockIdx.x & 7, j = blockIdx.x >> 3;    // 512 blocks, j 0..63
    int tm = x + ((j >> 4) << 3);                   // 0..31
    int tn = j & 15;                                // 0..15

    int srow = lane >> 2;
    int schk = (lane & 3) ^ (srow & 3);
    const bf16* asrc0 = A + (size_t)(tm * 128 + (2 * w) * 16 + srow) * DD + schk * 8;
    const bf16* asrc1 = asrc0 + (size_t)16 * DD;
    const bf16* wsrc  = W + (size_t)(tn * 64 + w * 16 + srow) * DD + schk * 8;
    char* adst0 = (char*)&As[0][0][0] + (2 * w) * 1024;
    char* adst1 = adst0 + 1024;
    char* wdst  = (char*)&Bs[0][0][0] + w * 1024;

    f32x4 acc[4][2];
#pragma unroll
    for (int i = 0; i < 4; ++i)
#pragma unroll
        for (int q = 0; q < 2; ++q) acc[i][q] = (f32x4){0.f, 0.f, 0.f, 0.f};

#pragma unroll
    for (int s = 0; s < 2; ++s) {
        gload_lds16(asrc0 + s * 32, adst0 + s * 8192);
        gload_lds16(asrc1 + s * 32, adst1 + s * 8192);
        gload_lds16(wsrc  + s * 32, wdst  + s * 4096);
    }

    for (int t0 = 0; t0 < 32; ++t0) {
        if (t0 + 2 < 32) {
            int s = t0 + 2;
            gload_lds16(asrc0 + s * 32, adst0 + (s & 3) * 8192);
            gload_lds16(asrc1 + s * 32, adst1 + (s & 3) * 8192);
            gload_lds16(wsrc  + s * 32, wdst  + (s & 3) * 4096);
        }
        if (t0 < 30)      { WAITV(6); }
        else if (t0 == 30){ WAITV(3); }
        else              { WAITV(0); }
        BAR();
        const char* al = (const char*)&As[0][0][0] + (t0 & 3) * 8192;
        const char* wl = (const char*)&Bs[0][0][0] + (t0 & 3) * 4096;
        bf16x8 af[4], bfr[2];
#pragma unroll
        for (int mt = 0; mt < 4; ++mt) {
            int row = wm * 64 + mt * 16 + c16;
            af[mt] = *(const bf16x8*)(al + row * 64 + ((quad ^ (row & 3)) << 4));
        }
#pragma unroll
        for (int nt = 0; nt < 2; ++nt) {
            int row = wn * 32 + nt * 16 + c16;
            bfr[nt] = *(const bf16x8*)(wl + row * 64 + ((quad ^ (row & 3)) << 4));
        }
#pragma unroll
        for (int mt = 0; mt < 4; ++mt)
#pragma unroll
            for (int nt = 0; nt < 2; ++nt)
                acc[mt][nt] = mfma16(af[mt], bfr[nt], acc[mt][nt]);
    }

#pragma unroll
    for (int nt = 0; nt < 2; ++nt) {
        int col = tn * 64 + wn * 32 + nt * 16 + c16;
        float bv = bias[col];
#pragma unroll
        for (int mt = 0; mt < 4; ++mt) {
            int r0 = tm * 128 + wm * 64 + mt * 16 + quad * 4;
#pragma unroll
            for (int r = 0; r < 4; ++r)
                C[(size_t)(r0 + r) * DD + col] = acc[mt][nt][r] + bv;
        }
    }
}

// ---------------------------------------------------------------------------
// col_stats5: partial column sums z_k = sum_{q in half} exp(s[q,k]).
// 512 blocks (2/CU); attn combines rz = 1/(z0+z1) in its prologue.
// ---------------------------------------------------------------------------
__global__ __launch_bounds__(512) void col_stats5(
    const bf16* __restrict__ Q, const bf16* __restrict__ Km,
    float* __restrict__ z0S, float* __restrict__ z1S)
{
    __shared__ __align__(16) bf16 Qlds[4][32][64];   // 16 KB

    int t = (int)threadIdx.x;
    int w = t >> 6, lane = t & 63;
    int c16 = lane & 15, quad = lane >> 4, ko = quad << 3;

    int x = blockIdx.x & 7, j = blockIdx.x >> 3;     // j 0..63
    int bh = ((j >> 4) << 3) + x;                    // 4 bh-groups
    int qh = (j >> 3) & 1;
    int kg = j & 7;
    int b = bh >> 4, h = bh & (HH - 1);
    int kbase = kg * 256 + w * 32;
    int q0base = qh * 1024;
    float* zS = qh ? z1S : z0S;

    bf16x8 kf[2][2];
#pragma unroll
    for (int g = 0; g < 2; ++g) {
        const bf16* kp =
            Km + ((size_t)(b * SS + kbase + g * 16 + c16)) * DD + h * DH + ko;
        kf[g][0] = *(const bf16x8*)kp;
        kf[g][1] = *(const bf16x8*)(kp + 32);
    }

    int srow  = ((w & 3) << 3) + (lane >> 3);
    int schnk = (lane & 7) ^ (srow & 7);
    const bf16* gsrc =
        Q + ((size_t)(b * SS + q0base + srow)) * DD + h * DH + schnk * 8;
    int ldsOff = (w & 3) << 10;
    bool stager = (w < 4);

    float z[2][4] = {{0.f,0.f,0.f,0.f},{0.f,0.f,0.f,0.f}};

    if (stager) {
        gload_lds16(gsrc, (char*)&Qlds[0][0][0] + ldsOff);
        gload_lds16(gsrc + (size_t)32 * DD, (char*)&Qlds[1][0][0] + ldsOff);
    }

    for (int t0 = 0; t0 < 32; ++t0) {
        if (t0 + 2 < 32 && stager)
            gload_lds16(gsrc + (size_t)(t0 + 2) * 32 * DD,
                        (char*)&Qlds[(t0 + 2) & 3][0][0] + ldsOff);
        if (t0 < 30)      { WAITV(2); }
        else if (t0 == 30){ WAITV(1); }
        else              { WAITV(0); }
        BAR();
        const char* ql = (const char*)&Qlds[t0 & 3][0][0];
#pragma unroll
        for (int qs = 0; qs < 2; ++qs) {
            int row = qs * 16 + c16;
            int p0  = quad ^ (row & 7);
            bf16x8 qf0 = *(const bf16x8*)(ql + row * 128 + p0 * 16);
            bf16x8 qf1 = *(const bf16x8*)(ql + row * 128 + (p0 ^ 4) * 16);
#pragma unroll
            for (int g = 0; g < 2; ++g) {
                f32x4 a = {0.f, 0.f, 0.f, 0.f};
                a = mfma16(kf[g][0], qf0, a);
                a = mfma16(kf[g][1], qf1, a);
#pragma unroll
                for (int r = 0; r < 4; ++r)
                    z[g][r] += __expf(a[r]);
            }
        }
    }

#pragma unroll
    for (int g = 0; g < 2; ++g)
#pragma unroll
        for (int r = 0; r < 4; ++r) {
#pragma unroll
            for (int off = 1; off < 16; off <<= 1)
                z[g][r] += __shfl_xor(z[g][r], off, 64);
        }
    if (c16 == 0) {
        size_t base = (size_t)bh * SS + kbase + quad * 4;
#pragma unroll
        for (int g = 0; g < 2; ++g)
#pragma unroll
            for (int r = 0; r < 4; ++r)
                zS[base + g * 16 + r] = z[g][r];
    }
}

// ---------------------------------------------------------------------------
// attn_ctx7 (round-8 proven, 67.6us): 256 blocks x 8 waves (K/V tile shared
// by all 8 waves), 4 LDS buffers, 2 ahead, counted vmcnt(2)/(1)/(0), rz in
// LDS (no globals in k-loop), V swizzle at bank floor.
// ---------------------------------------------------------------------------
__global__ __launch_bounds__(512) void attn_ctx7(
    const bf16* __restrict__ Q, const bf16* __restrict__ Km,
    const bf16* __restrict__ Vt, const float* __restrict__ z0S,
    const float* __restrict__ z1S, bf16* __restrict__ ctx)
{
    __shared__ __align__(16) char lds[4][8192];   // per buf: K 4KB | V 4KB
    __shared__ __align__(16) float rzlds[2048];   // 8 KB

    int t = (int)threadIdx.x;
    int w = t >> 6, lane = t & 63;
    int c16 = lane & 15, quad = lane >> 4, ko = quad << 3;

    int bid = blockIdx.x;
    int x = bid & 7, j = bid >> 3;
    int bh = ((j >> 3) << 3) + x;
    int qg = j & 7;
    int b = bh >> 4, h = bh & (HH - 1);
    int qt0 = qg * 16 + w * 2;

    const bf16* qp0 = Q + ((size_t)(b * SS + qt0 * 16 + c16)) * DD + h * DH + ko;
    bf16x8 qa0 = *(const bf16x8*)qp0;
    bf16x8 qa1 = *(const bf16x8*)(qp0 + 32);
    const bf16* qp1 = qp0 + (size_t)16 * DD;
    bf16x8 qb0 = *(const bf16x8*)qp1;
    bf16x8 qb1 = *(const bf16x8*)(qp1 + 32);

    // --- prologue A: combine z halves into rzlds (one-time) ---
    {
        const float* z0p = z0S + (size_t)bh * SS + (w << 8) + lane * 4;
        const float* z1p = z1S + (size_t)bh * SS + (w << 8) + lane * 4;
        gload_lds16(z0p, (char*)&lds[0][0] + (w << 10));
        gload_lds16(z1p, (char*)&lds[1][0] + (w << 10));
        WAITV(0);
        __syncthreads();
        f32x4 z0 = *(const f32x4*)&lds[0][t * 16];
        f32x4 z1 = *(const f32x4*)&lds[1][t * 16];
        f32x4 rz;
#pragma unroll
        for (int r = 0; r < 4; ++r) rz[r] = 1.0f / (z0[r] + z1[r]);
        *(f32x4*)&rzlds[t * 4] = rz;
        __syncthreads();
    }

    // --- staging setup ---
    const bf16* gsrc;
    int ldsOff;
    bool isK = (w < 4);
    if (isK) {
        int row   = (w << 3) + (lane >> 3);
        int chunk = (lane & 7) ^ (row & 7);
        gsrc  = Km + ((size_t)(b * SS + row)) * DD + h * DH + chunk * 8;
        ldsOff = (w << 10);
    } else {
        int i = w - 4;
        int row   = (i << 4) + (lane >> 2);
        int chunk = (lane & 3) ^ ((lane >> 3) & 3);   // (row>>1)&3 swizzle
        gsrc  = Vt + ((size_t)(b * DD + h * DH + row)) * SS + chunk * 8;
        ldsOff = 4096 + (i << 10);
    }

    int kread  = c16 * 128 + ((quad ^ (c16 & 7)) << 4);
    int vread0 = c16 * 64 + (((quad >> 1) ^ ((c16 >> 1) & 3)) << 4)
               + ((quad & 1) << 3);

    f32x4 oa[4] = {{0,0,0,0},{0,0,0,0},{0,0,0,0},{0,0,0,0}};
    f32x4 ob[4] = {{0,0,0,0},{0,0,0,0},{0,0,0,0},{0,0,0,0}};

    // prologue B: stages 0,1
    gload_lds16(gsrc, &lds[0][ldsOff]);
    gload_lds16(isK ? gsrc + (size_t)32 * DD : gsrc + 32, &lds[1][ldsOff]);

    for (int t0 = 0; t0 < 64; ++t0) {
        if (t0 + 2 < 64) {
            int s = t0 + 2;
            const bf16* g = isK ? gsrc + (size_t)(s * 32) * DD : gsrc + s * 32;
            gload_lds16(g, &lds[s & 3][ldsOff]);
        }
        if (t0 < 62)      { WAITV(2); }
        else if (t0 == 62){ WAITV(1); }
        else              { WAITV(0); }
        BAR();
        const char* kl = &lds[t0 & 3][0];
        const char* vl = &lds[t0 & 3][4096];
#pragma unroll
        for (int ks = 0; ks < 2; ++ks) {
            int kb0 = kread + ks * 2048;
            bf16x8 kf0 = *(const bf16x8*)(kl + kb0);
            bf16x8 kf1 = *(const bf16x8*)(kl + (kb0 ^ 64));
            f32x4 z4 = *(const f32x4*)&rzlds[t0 * 32 + ks * 16 + quad * 4];
            f32x4 sa = {0,0,0,0}, sb = {0,0,0,0};
            sa = mfma16(kf0, qa0, sa);
            sa = mfma16(kf1, qa1, sa);
            sb = mfma16(kf0, qb0, sb);
            sb = mfma16(kf1, qb1, sb);

            union { bf16x4 b; short4v s; } pa, pb;
#pragma unroll
            for (int r = 0; r < 4; ++r) {
                pa.b[r] = (bf16)(__expf(sa[r]) * z4[r]);
                pb.b[r] = (bf16)(__expf(sb[r]) * z4[r]);
            }
            int vb0 = ks ? (vread0 ^ 32) : vread0;
#pragma unroll
            for (int dt = 0; dt < 4; ++dt) {
                short4v vf = *(const short4v*)(vl + vb0 + dt * 1024);
                oa[dt] = mfma16k16(pa.s, vf, oa[dt]);
                ob[dt] = mfma16k16(pb.s, vf, ob[dt]);
            }
        }
    }

    size_t orow = ((size_t)(b * SS + qt0 * 16 + quad * 4)) * DD + h * DH + c16;
#pragma unroll
    for (int dt = 0; dt < 4; ++dt)
#pragma unroll
        for (int r = 0; r < 4; ++r) {
            ctx[orow + (size_t)r * DD + dt * 16] = (bf16)oa[dt][r];
            ctx[orow + (size_t)(16 + r) * DD + dt * 16] = (bf16)ob[dt][r];
        }
}

extern "C" void kernel_launch(void* const* d_in, const int* in_sizes, int n_in,
                              void* d_out, int out_size, void* d_ws, size_t ws_size,
                              hipStream_t stream) {
    const float* query = (const float*)d_in[0];
    const float* key   = (const float*)d_in[1];
    const float* value = (const float*)d_in[2];
    const float* Wq = (const float*)d_in[3];
    const float* bq = (const float*)d_in[4];
    const float* Wk = (const float*)d_in[5];
    const float* bk = (const float*)d_in[6];
    const float* Wv = (const float*)d_in[7];
    const float* bv = (const float*)d_in[8];
    const float* Wo = (const float*)d_in[9];
    const float* bo = (const float*)d_in[10];
    float* out = (float*)d_out;

    if (n_in != 11 || in_sizes[0] != (int)NTOK || in_sizes[3] != DD * DD ||
        in_sizes[4] != DD || out_size != (int)NTOK) {
        hipLaunchKernelGGL(signal_f, dim3(1), dim3(64), 0, stream, out, -64.0f);
        return;
    }

    bf16* Qs  = (bf16*)d_ws;          // 0.125-scaled Q projection
    bf16* Ks  = Qs + NTOK;
    bf16* Vt  = Ks + NTOK;            // transposed V: [b][d][s]
    bf16* Cs  = Vt + NTOK;            // ctx; pre-attn aliased as bf16 weights
    float* z0S = (float*)(Cs + NTOK); // partial column sums (q-half 0 / 1)
    float* z1S = z0S + STATN;

    bf16* Wqb = Cs;                   // 3x 2MB bf16 weights (dead until attn)
    bf16* Wkb = Cs + (size_t)DD * DD;
    bf16* Wvb = Cs + (size_t)2 * DD * DD;
    bf16* WoB = Qs;                   // Wo bf16, written AFTER attn (Qs dead)

    hipLaunchKernelGGL(cvt_w3, dim3(512, 3), dim3(256), 0, stream,
                       Wq, Wk, Wv, Wqb, Wkb, Wvb);

    hipLaunchKernelGGL(qkv8, dim3(768), dim3(256), 0, stream,
                       query, key, value, Wqb, Wkb, Wvb, bq, bk, bv,
                       Qs, Ks, Vt);

    hipLaunchKernelGGL(col_stats5, dim3(512), dim3(512), 0, stream,
                       Qs, Ks, z0S, z1S);

    hipLaunchKernelGGL(attn_ctx7, dim3(256), dim3(512), 0, stream,
                       Qs, Ks, Vt, z0S, z1S, Cs);

    hipLaunchKernelGGL(cvt_bf16, dim3(512), dim3(256), 0, stream, Wo, WoB);

    hipLaunchKernelGGL(gemm7, dim3(512), dim3(256), 0, stream, Cs, WoB, bo, out);
}